// Round 14
// baseline (575.510 us; speedup 1.0000x reference)
//
#include <hip/hip_runtime.h>
#include <hip/hip_bf16.h>

// SphericalAttention on MI355X (gfx950).  ROUND 14: loop-fission pipeline in
// attn. KV group = 256 = 4 sub-tiles: phase 1 (QK+softmax+pack x4, no barrier
// between subs -> loads pipeline), ONE lgkmcnt barrier, phase 2 (read P +
// V-load + rescale-by-saved-al + PV x4). Arithmetic identical to R13 (green);
// only instruction scheduling changes. pbuf 16x264/wave (33.8KB/block).
// Inputs fp32; output fp32. N=4096, C=512, nh=8, dh=64.

typedef __attribute__((ext_vector_type(8))) short bf16x8;
typedef __attribute__((ext_vector_type(4))) float f32x4;

#define MFMA16(a, b, c) __builtin_amdgcn_mfma_f32_16x16x32_bf16(a, b, c, 0, 0, 0)

__device__ __forceinline__ unsigned short f2b(float f) {
    union { float f; unsigned int i; } v;
    v.f = f;
    unsigned int lsb = (v.i >> 16) & 1u;
    unsigned int r = v.i + 0x7fffu + lsb;   // RNE
    return (unsigned short)(r >> 16);
}

// ---------------------------------------------------------------- fp32 -> bf16
__global__ __launch_bounds__(256) void cvt_kernel(
    const float* __restrict__ in, unsigned short* __restrict__ out, int n) {
    int i = (blockIdx.x * 256 + threadIdx.x) * 4;
    if (i + 3 < n) {
        float4 v = *(const float4*)(in + i);
        ushort4 u;
        u.x = f2b(v.x); u.y = f2b(v.y); u.z = f2b(v.z); u.w = f2b(v.w);
        *(ushort4*)(out + i) = u;
    }
}

// ---------------------------------------------------------------- dist + stats
__global__ __launch_bounds__(256) void dist_kernel(
    const float* __restrict__ lat, const float* __restrict__ lon,
    float* __restrict__ dist, double* __restrict__ partials) {
    __shared__ float sl_i[64], sc_i[64], so_i[64];
    __shared__ float sl_j[64], sc_j[64], so_j[64];
    __shared__ double rs[256], rs2[256];

    int bi = blockIdx.x;
    int i0 = (bi >> 6) << 6;
    int j0 = (bi & 63) << 6;
    int tid = threadIdx.x;

    if (tid < 64) {
        float la = lat[i0 + tid];
        sl_i[tid] = la; sc_i[tid] = __cosf(la); so_i[tid] = lon[i0 + tid];
    } else if (tid < 128) {
        int t = tid - 64;
        float la = lat[j0 + t];
        sl_j[t] = la; sc_j[t] = __cosf(la); so_j[t] = lon[j0 + t];
    }
    __syncthreads();

    double s = 0.0, s2 = 0.0;
    int col = tid & 63;
    float latj = sl_j[col], cj = sc_j[col], lonj = so_j[col];
#pragma unroll
    for (int kk = 0; kk < 16; kk++) {
        int row = (kk << 2) + (tid >> 6);
        float dlat = latj - sl_i[row];
        float dlon = lonj - so_i[row];
        float h1 = __sinf(0.5f * dlat);
        float h2 = __sinf(0.5f * dlon);
        float a = h1 * h1 + sc_i[row] * cj * h2 * h2;
        a = fminf(fmaxf(a, 0.0f), 1.0f);
        float d = 2.0f * asinf(sqrtf(a));
        dist[(size_t)(i0 + row) * 4096 + j0 + col] = d;
        s += (double)d;
        s2 += (double)d * (double)d;
    }
    rs[tid] = s; rs2[tid] = s2;
    __syncthreads();
    for (int off = 128; off > 0; off >>= 1) {
        if (tid < off) { rs[tid] += rs[tid + off]; rs2[tid] += rs2[tid + off]; }
        __syncthreads();
    }
    if (tid == 0) {
        partials[2 * bi] = rs[0];
        partials[2 * bi + 1] = rs2[0];
    }
}

__global__ __launch_bounds__(256) void stats_kernel(
    const double* __restrict__ partials, float* __restrict__ neg_inv_std) {
    __shared__ double rs[256], rs2[256];
    int tid = threadIdx.x;
    double s = 0.0, s2 = 0.0;
    for (int i = tid; i < 4096; i += 256) {
        s += partials[2 * i];
        s2 += partials[2 * i + 1];
    }
    rs[tid] = s; rs2[tid] = s2;
    __syncthreads();
    for (int off = 128; off > 0; off >>= 1) {
        if (tid < off) { rs[tid] += rs[tid + off]; rs2[tid] += rs2[tid + off]; }
        __syncthreads();
    }
    if (tid == 0) {
        double n = 16777216.0;
        double mean = rs[0] / n;
        double var = (rs2[0] - n * mean * mean) / (n - 1.0);  // ddof=1
        *neg_inv_std = (float)(-1.0 / sqrt(var));
    }
}

// ---------------------------------------------------------------- QKV GEMM
__global__ __launch_bounds__(256) void qkv_gemm(
    const unsigned short* __restrict__ x, const unsigned short* __restrict__ w,
    const float* __restrict__ b,
    unsigned short* __restrict__ q, unsigned short* __restrict__ k,
    unsigned short* __restrict__ vt) {
    int lane = threadIdx.x & 63, wave = threadIdx.x >> 6;
    int l16 = lane & 15, quad = lane >> 4;
    int m0 = blockIdx.y * 64 + wave * 16;
    int n0 = blockIdx.x * 64;

    const unsigned short* arow = x + (size_t)(m0 + l16) * 512 + quad * 8;
    f32x4 acc[4];
#pragma unroll
    for (int nb = 0; nb < 4; nb++) acc[nb] = (f32x4){0.f, 0.f, 0.f, 0.f};

    for (int k0 = 0; k0 < 512; k0 += 32) {
        bf16x8 af = *(const bf16x8*)(arow + k0);
#pragma unroll
        for (int nb = 0; nb < 4; nb++) {
            bf16x8 bf = *(const bf16x8*)(w + (size_t)(n0 + nb * 16 + l16) * 512 + k0 + quad * 8);
            acc[nb] = MFMA16(af, bf, acc[nb]);
        }
    }
#pragma unroll
    for (int nb = 0; nb < 4; nb++) {
        int j = n0 + nb * 16 + l16;
        float bj = b[j];
        int s = j >> 9;         // 0=q 1=k 2=v
        int rem = j & 511;
        int h = rem >> 6, d = rem & 63;
#pragma unroll
        for (int r = 0; r < 4; r++) {
            int n = m0 + quad * 4 + r;
            unsigned short u = f2b(acc[nb][r] + bj);
            if (s == 0)      q[((size_t)h * 4096 + n) * 64 + d] = u;
            else if (s == 1) k[((size_t)h * 4096 + n) * 64 + d] = u;
            else             vt[((size_t)h * 64 + d) * 4096 + n] = u;
        }
    }
}

// ---------------------------------------------------------------- flash attention
// Block = (head, 16 q-rows); 4 waves x 1024-wide KV quarters; online softmax.
// KV group = 256: phase 1 = 4x(QK+softmax+pack), 1 barrier, phase 2 =
// 4x(readP + V + rescale(al[sub]) + PV). Math identical to R13.
__global__ __launch_bounds__(256) void attn_kernel(
    const unsigned short* __restrict__ q, const unsigned short* __restrict__ k,
    const unsigned short* __restrict__ vt, const float* __restrict__ dist,
    const float* __restrict__ nis_p, unsigned short* __restrict__ att) {
    __shared__ __align__(16) char smem[33792];  // 4 waves x (16 x 264) u16
    int lane = threadIdx.x & 63, wave = threadIdx.x >> 6;
    int l16 = lane & 15, quad = lane >> 4;
    int h = blockIdx.x >> 8;
    int q0 = (blockIdx.x & 255) * 16;
    int kvbase = wave * 1024;
    float nis = *nis_p;
    const float scale = 0.125f;

    unsigned short* pb = (unsigned short*)smem + wave * 4224;   // 16 x 264

    const unsigned short* qbase = q + ((size_t)h * 4096 + q0 + l16) * 64 + quad * 8;
    bf16x8 qf0 = *(const bf16x8*)(qbase);
    bf16x8 qf1 = *(const bf16x8*)(qbase + 32);

    f32x4 o[4];
    float m[4], lam[4];
#pragma unroll
    for (int r = 0; r < 4; r++) {
        m[r] = -1e30f; lam[r] = 0.f;
        o[0][r] = 0.f; o[1][r] = 0.f; o[2][r] = 0.f; o[3][r] = 0.f;
    }

    for (int kv0 = kvbase; kv0 < kvbase + 1024; kv0 += 256) {
        float al[4][4];                    // [sub][r]
        // ================= phase 1: QK + softmax + pack, 4 subs, no barrier
#pragma unroll
        for (int sub = 0; sub < 4; sub++) {
            int kvs = kv0 + sub * 64;
            f32x4 s[4];
#pragma unroll
            for (int cb = 0; cb < 4; cb++) {
                const unsigned short* kbase =
                    k + ((size_t)h * 4096 + kvs + cb * 16 + l16) * 64 + quad * 8;
                bf16x8 kf0 = *(const bf16x8*)(kbase);
                bf16x8 kf1 = *(const bf16x8*)(kbase + 32);
                f32x4 z = (f32x4){0.f, 0.f, 0.f, 0.f};
                z = MFMA16(qf0, kf0, z);
                z = MFMA16(qf1, kf1, z);
                s[cb] = z;
            }
#pragma unroll
            for (int r = 0; r < 4; r++) {
                const float* drow =
                    dist + (size_t)(q0 + quad * 4 + r) * 4096 + kvs + l16;
#pragma unroll
                for (int cb = 0; cb < 4; cb++)
                    s[cb][r] = s[cb][r] * scale + drow[cb * 16] * nis;
            }
            float mt[4];
#pragma unroll
            for (int r = 0; r < 4; r++) {
                float v = fmaxf(fmaxf(s[0][r], s[1][r]), fmaxf(s[2][r], s[3][r]));
#pragma unroll
                for (int off = 1; off < 16; off <<= 1)
                    v = fmaxf(v, __shfl_xor(v, off, 64));
                mt[r] = v;
            }
#pragma unroll
            for (int r = 0; r < 4; r++) {
                float mn = fmaxf(m[r], mt[r]);
                al[sub][r] = __expf(m[r] - mn);
                m[r] = mn;
            }
            float ts[4] = {0.f, 0.f, 0.f, 0.f};
#pragma unroll
            for (int cb = 0; cb < 4; cb++)
#pragma unroll
                for (int r = 0; r < 4; r++) {
                    float p = __expf(s[cb][r] - m[r]);
                    ts[r] += p;
                    s[cb][r] = p;
                }
#pragma unroll
            for (int r = 0; r < 4; r++)
                lam[r] = lam[r] * al[sub][r] + ts[r];
#pragma unroll
            for (int cb = 0; cb < 4; cb++)
#pragma unroll
                for (int r = 0; r < 4; r++)
                    pb[(quad * 4 + r) * 264 + sub * 64 + cb * 16 + l16] =
                        f2b(s[cb][r]);
        }
        // ================= one barrier per 256 columns
        asm volatile("s_waitcnt lgkmcnt(0)" ::: "memory");
        // ================= phase 2: read P, load V, rescale, PV MFMA
#pragma unroll
        for (int sub = 0; sub < 4; sub++) {
            int kvs = kv0 + sub * 64;
            bf16x8 pf0 = *(const bf16x8*)(pb + l16 * 264 + sub * 64 + quad * 8);
            bf16x8 pf1 = *(const bf16x8*)(pb + l16 * 264 + sub * 64 + 32 + quad * 8);
#pragma unroll
            for (int r = 0; r < 4; r++) {
                float a = al[sub][r];
                o[0][r] *= a; o[1][r] *= a; o[2][r] *= a; o[3][r] *= a;
            }
#pragma unroll
            for (int db = 0; db < 4; db++) {
                const unsigned short* vbase =
                    vt + ((size_t)h * 64 + db * 16 + l16) * 4096 + kvs + quad * 8;
                bf16x8 vf0 = *(const bf16x8*)(vbase);
                bf16x8 vf1 = *(const bf16x8*)(vbase + 32);
                o[db] = MFMA16(pf0, vf0, o[db]);
                o[db] = MFMA16(pf1, vf1, o[db]);
            }
        }
    }

    // deferred row-sum reduction
#pragma unroll
    for (int r = 0; r < 4; r++)
#pragma unroll
        for (int off = 1; off < 16; off <<= 1)
            lam[r] += __shfl_xor(lam[r], off, 64);

    // -------- block-level merge of 4 KV-chunk partials
    __syncthreads();                       // all waves done with pbuf
    float* obuf = (float*)smem;            // [4 chunk][16 row][64 d]
    float* mlbuf = (float*)(smem + 16384); // [4 chunk][16 row][2]
#pragma unroll
    for (int db = 0; db < 4; db++)
#pragma unroll
        for (int r = 0; r < 4; r++)
            obuf[(wave * 16 + quad * 4 + r) * 64 + db * 16 + l16] = o[db][r];
    if (l16 == 0)
#pragma unroll
        for (int r = 0; r < 4; r++) {
            mlbuf[(wave * 16 + quad * 4 + r) * 2 + 0] = m[r];
            mlbuf[(wave * 16 + quad * 4 + r) * 2 + 1] = lam[r];
        }
    __syncthreads();

    int d = threadIdx.x & 63;
#pragma unroll
    for (int i = 0; i < 4; i++) {
        int row = (threadIdx.x >> 6) * 4 + i;
        float m0c = mlbuf[(0 * 16 + row) * 2], m1c = mlbuf[(1 * 16 + row) * 2];
        float m2c = mlbuf[(2 * 16 + row) * 2], m3c = mlbuf[(3 * 16 + row) * 2];
        float M = fmaxf(fmaxf(m0c, m1c), fmaxf(m2c, m3c));
        float e0 = __expf(m0c - M), e1 = __expf(m1c - M);
        float e2 = __expf(m2c - M), e3 = __expf(m3c - M);
        float L = mlbuf[(0 * 16 + row) * 2 + 1] * e0 + mlbuf[(1 * 16 + row) * 2 + 1] * e1
                + mlbuf[(2 * 16 + row) * 2 + 1] * e2 + mlbuf[(3 * 16 + row) * 2 + 1] * e3;
        float O = obuf[(0 * 16 + row) * 64 + d] * e0 + obuf[(1 * 16 + row) * 64 + d] * e1
                + obuf[(2 * 16 + row) * 64 + d] * e2 + obuf[(3 * 16 + row) * 64 + d] * e3;
        att[(size_t)(q0 + row) * 512 + h * 64 + d] = f2b(O / L);
    }
}

// ---------------------------------------------------------------- output GEMM (fp32 store)
__global__ __launch_bounds__(256) void out_gemm(
    const unsigned short* __restrict__ att, const unsigned short* __restrict__ w,
    const float* __restrict__ b, float* __restrict__ out) {
    int lane = threadIdx.x & 63, wave = threadIdx.x >> 6;
    int l16 = lane & 15, quad = lane >> 4;
    int m0 = blockIdx.y * 64 + wave * 16;
    int n0 = blockIdx.x * 64;

    const unsigned short* arow = att + (size_t)(m0 + l16) * 512 + quad * 8;
    f32x4 acc[4];
#pragma unroll
    for (int nb = 0; nb < 4; nb++) acc[nb] = (f32x4){0.f, 0.f, 0.f, 0.f};

    for (int k0 = 0; k0 < 512; k0 += 32) {
        bf16x8 af = *(const bf16x8*)(arow + k0);
#pragma unroll
        for (int nb = 0; nb < 4; nb++) {
            bf16x8 bf = *(const bf16x8*)(w + (size_t)(n0 + nb * 16 + l16) * 512 + k0 + quad * 8);
            acc[nb] = MFMA16(af, bf, acc[nb]);
        }
    }
#pragma unroll
    for (int nb = 0; nb < 4; nb++) {
        float bj = b[n0 + nb * 16 + l16];
#pragma unroll
        for (int r = 0; r < 4; r++)
            out[(size_t)(m0 + quad * 4 + r) * 512 + n0 + nb * 16 + l16] =
                acc[nb][r] + bj;
    }
}

extern "C" void kernel_launch(void* const* d_in, const int* in_sizes, int n_in,
                              void* d_out, int out_size, void* d_ws, size_t ws_size,
                              hipStream_t stream) {
    const float* x    = (const float*)d_in[0];
    const float* lat  = (const float*)d_in[1];
    const float* lon  = (const float*)d_in[2];
    const float* wqkv = (const float*)d_in[3];
    const float* bqkv = (const float*)d_in[4];
    const float* wout = (const float*)d_in[5];
    const float* bout = (const float*)d_in[6];
    float* out = (float*)d_out;

    char* ws = (char*)d_ws;
    float* dist        = (float*)ws;                                  // 64 MiB
    double* partials   = (double*)(ws + 67108864);                    // 64 KiB
    float* nis         = (float*)(ws + 67108864 + 65536);             // 64 B
    unsigned short* q  = (unsigned short*)(ws + 67108864 + 65600);
    unsigned short* k  = q  + (size_t)8 * 4096 * 64;   // 4 MiB each
    unsigned short* vt = k  + (size_t)8 * 4096 * 64;
    unsigned short* att = vt + (size_t)8 * 4096 * 64;
    unsigned short* xb  = att + (size_t)4096 * 512;
    unsigned short* wqb = xb  + (size_t)4096 * 512;
    unsigned short* wob = wqb + (size_t)1536 * 512;

    cvt_kernel<<<2048, 256, 0, stream>>>(x, xb, 4096 * 512);
    cvt_kernel<<<768, 256, 0, stream>>>(wqkv, wqb, 1536 * 512);
    cvt_kernel<<<256, 256, 0, stream>>>(wout, wob, 512 * 512);
    dist_kernel<<<4096, 256, 0, stream>>>(lat, lon, dist, partials);
    stats_kernel<<<1, 256, 0, stream>>>(partials, nis);
    qkv_gemm<<<dim3(24, 64), 256, 0, stream>>>(xb, wqb, bqkv, q, k, vt);
    attn_kernel<<<2048, 256, 0, stream>>>(q, k, vt, dist, nis, att);
    out_gemm<<<dim3(8, 64), 256, 0, stream>>>(att, wob, bout, out);
}

// Round 15
// 477.894 us; speedup vs baseline: 1.2043x; 1.2043x over previous
//
#include <hip/hip_runtime.h>
#include <hip/hip_bf16.h>

// SphericalAttention on MI355X (gfx950).  ROUND 15: R13 (green, 482us) with
// the per-iteration asm "memory" clobber REMOVED from attn. The clobber only
// enforced the per-wave LDS pack->read order, which the compiler already
// preserves (unprovable aliasing on pb => ordered + precise lgkmcnt wait);
// but it also blocked hoisting next-iteration K/dist loads and V loads across
// the LDS dependency — the diagnosed latency exposure. Pack store typed as
// short to match bf16x8 element type (alias soundness). R14's fission is
// reverted: its +LDS/+VGPR cost dropped occupancy 45->30% and regressed.
// Inputs fp32; output fp32. N=4096, C=512, nh=8, dh=64.

typedef __attribute__((ext_vector_type(8))) short bf16x8;
typedef __attribute__((ext_vector_type(4))) float f32x4;

#define MFMA16(a, b, c) __builtin_amdgcn_mfma_f32_16x16x32_bf16(a, b, c, 0, 0, 0)

__device__ __forceinline__ unsigned short f2b(float f) {
    union { float f; unsigned int i; } v;
    v.f = f;
    unsigned int lsb = (v.i >> 16) & 1u;
    unsigned int r = v.i + 0x7fffu + lsb;   // RNE
    return (unsigned short)(r >> 16);
}

// ---------------------------------------------------------------- fp32 -> bf16
__global__ __launch_bounds__(256) void cvt_kernel(
    const float* __restrict__ in, unsigned short* __restrict__ out, int n) {
    int i = (blockIdx.x * 256 + threadIdx.x) * 4;
    if (i + 3 < n) {
        float4 v = *(const float4*)(in + i);
        ushort4 u;
        u.x = f2b(v.x); u.y = f2b(v.y); u.z = f2b(v.z); u.w = f2b(v.w);
        *(ushort4*)(out + i) = u;
    }
}

// ---------------------------------------------------------------- dist + stats
__global__ __launch_bounds__(256) void dist_kernel(
    const float* __restrict__ lat, const float* __restrict__ lon,
    float* __restrict__ dist, double* __restrict__ partials) {
    __shared__ float sl_i[64], sc_i[64], so_i[64];
    __shared__ float sl_j[64], sc_j[64], so_j[64];
    __shared__ double rs[256], rs2[256];

    int bi = blockIdx.x;
    int i0 = (bi >> 6) << 6;
    int j0 = (bi & 63) << 6;
    int tid = threadIdx.x;

    if (tid < 64) {
        float la = lat[i0 + tid];
        sl_i[tid] = la; sc_i[tid] = __cosf(la); so_i[tid] = lon[i0 + tid];
    } else if (tid < 128) {
        int t = tid - 64;
        float la = lat[j0 + t];
        sl_j[t] = la; sc_j[t] = __cosf(la); so_j[t] = lon[j0 + t];
    }
    __syncthreads();

    double s = 0.0, s2 = 0.0;
    int col = tid & 63;
    float latj = sl_j[col], cj = sc_j[col], lonj = so_j[col];
#pragma unroll
    for (int kk = 0; kk < 16; kk++) {
        int row = (kk << 2) + (tid >> 6);
        float dlat = latj - sl_i[row];
        float dlon = lonj - so_i[row];
        float h1 = __sinf(0.5f * dlat);
        float h2 = __sinf(0.5f * dlon);
        float a = h1 * h1 + sc_i[row] * cj * h2 * h2;
        a = fminf(fmaxf(a, 0.0f), 1.0f);
        float d = 2.0f * asinf(sqrtf(a));
        dist[(size_t)(i0 + row) * 4096 + j0 + col] = d;
        s += (double)d;
        s2 += (double)d * (double)d;
    }
    rs[tid] = s; rs2[tid] = s2;
    __syncthreads();
    for (int off = 128; off > 0; off >>= 1) {
        if (tid < off) { rs[tid] += rs[tid + off]; rs2[tid] += rs2[tid + off]; }
        __syncthreads();
    }
    if (tid == 0) {
        partials[2 * bi] = rs[0];
        partials[2 * bi + 1] = rs2[0];
    }
}

__global__ __launch_bounds__(256) void stats_kernel(
    const double* __restrict__ partials, float* __restrict__ neg_inv_std) {
    __shared__ double rs[256], rs2[256];
    int tid = threadIdx.x;
    double s = 0.0, s2 = 0.0;
    for (int i = tid; i < 4096; i += 256) {
        s += partials[2 * i];
        s2 += partials[2 * i + 1];
    }
    rs[tid] = s; rs2[tid] = s2;
    __syncthreads();
    for (int off = 128; off > 0; off >>= 1) {
        if (tid < off) { rs[tid] += rs[tid + off]; rs2[tid] += rs2[tid + off]; }
        __syncthreads();
    }
    if (tid == 0) {
        double n = 16777216.0;
        double mean = rs[0] / n;
        double var = (rs2[0] - n * mean * mean) / (n - 1.0);  // ddof=1
        *neg_inv_std = (float)(-1.0 / sqrt(var));
    }
}

// ---------------------------------------------------------------- QKV GEMM
__global__ __launch_bounds__(256) void qkv_gemm(
    const unsigned short* __restrict__ x, const unsigned short* __restrict__ w,
    const float* __restrict__ b,
    unsigned short* __restrict__ q, unsigned short* __restrict__ k,
    unsigned short* __restrict__ vt) {
    int lane = threadIdx.x & 63, wave = threadIdx.x >> 6;
    int l16 = lane & 15, quad = lane >> 4;
    int m0 = blockIdx.y * 64 + wave * 16;
    int n0 = blockIdx.x * 64;

    const unsigned short* arow = x + (size_t)(m0 + l16) * 512 + quad * 8;
    f32x4 acc[4];
#pragma unroll
    for (int nb = 0; nb < 4; nb++) acc[nb] = (f32x4){0.f, 0.f, 0.f, 0.f};

    for (int k0 = 0; k0 < 512; k0 += 32) {
        bf16x8 af = *(const bf16x8*)(arow + k0);
#pragma unroll
        for (int nb = 0; nb < 4; nb++) {
            bf16x8 bf = *(const bf16x8*)(w + (size_t)(n0 + nb * 16 + l16) * 512 + k0 + quad * 8);
            acc[nb] = MFMA16(af, bf, acc[nb]);
        }
    }
#pragma unroll
    for (int nb = 0; nb < 4; nb++) {
        int j = n0 + nb * 16 + l16;
        float bj = b[j];
        int s = j >> 9;         // 0=q 1=k 2=v
        int rem = j & 511;
        int h = rem >> 6, d = rem & 63;
#pragma unroll
        for (int r = 0; r < 4; r++) {
            int n = m0 + quad * 4 + r;
            unsigned short u = f2b(acc[nb][r] + bj);
            if (s == 0)      q[((size_t)h * 4096 + n) * 64 + d] = u;
            else if (s == 1) k[((size_t)h * 4096 + n) * 64 + d] = u;
            else             vt[((size_t)h * 64 + d) * 4096 + n] = u;
        }
    }
}

// ---------------------------------------------------------------- flash attention
// Block = (head, 16 q-rows); 4 waves x 1024-wide KV quarters; online softmax
// with lambda-deferral (R13). No asm clobber: compiler keeps the pb
// write->read order itself and is free to pipeline global loads.
__global__ __launch_bounds__(256) void attn_kernel(
    const unsigned short* __restrict__ q, const unsigned short* __restrict__ k,
    const unsigned short* __restrict__ vt, const float* __restrict__ dist,
    const float* __restrict__ nis_p, unsigned short* __restrict__ att) {
    __shared__ __align__(16) char smem[16896];   // pbuf 4x(16x72)u16 | obuf+mlbuf
    int lane = threadIdx.x & 63, wave = threadIdx.x >> 6;
    int l16 = lane & 15, quad = lane >> 4;
    int h = blockIdx.x >> 8;
    int q0 = (blockIdx.x & 255) * 16;
    int kvbase = wave * 1024;
    float nis = *nis_p;
    const float scale = 0.125f;

    short* pb = (short*)smem + wave * 1152;   // 16 x 72

    const unsigned short* qbase = q + ((size_t)h * 4096 + q0 + l16) * 64 + quad * 8;
    bf16x8 qf0 = *(const bf16x8*)(qbase);
    bf16x8 qf1 = *(const bf16x8*)(qbase + 32);

    f32x4 o[4];
    float m[4], lam[4];
#pragma unroll
    for (int r = 0; r < 4; r++) {
        m[r] = -1e30f; lam[r] = 0.f;
        o[0][r] = 0.f; o[1][r] = 0.f; o[2][r] = 0.f; o[3][r] = 0.f;
    }

    for (int kv0 = kvbase; kv0 < kvbase + 1024; kv0 += 64) {
        f32x4 s[4];
#pragma unroll
        for (int cb = 0; cb < 4; cb++) {
            const unsigned short* kbase =
                k + ((size_t)h * 4096 + kv0 + cb * 16 + l16) * 64 + quad * 8;
            bf16x8 kf0 = *(const bf16x8*)(kbase);
            bf16x8 kf1 = *(const bf16x8*)(kbase + 32);
            f32x4 z = (f32x4){0.f, 0.f, 0.f, 0.f};
            z = MFMA16(qf0, kf0, z);
            z = MFMA16(qf1, kf1, z);
            s[cb] = z;
        }
#pragma unroll
        for (int r = 0; r < 4; r++) {
            const float* drow = dist + (size_t)(q0 + quad * 4 + r) * 4096 + kv0 + l16;
#pragma unroll
            for (int cb = 0; cb < 4; cb++)
                s[cb][r] = s[cb][r] * scale + drow[cb * 16] * nis;
        }
        // row max
        float mt[4];
#pragma unroll
        for (int r = 0; r < 4; r++) {
            float v = fmaxf(fmaxf(s[0][r], s[1][r]), fmaxf(s[2][r], s[3][r]));
#pragma unroll
            for (int off = 1; off < 16; off <<= 1)
                v = fmaxf(v, __shfl_xor(v, off, 64));
            mt[r] = v;
        }
        float al[4];
#pragma unroll
        for (int r = 0; r < 4; r++) {
            float mn = fmaxf(m[r], mt[r]);
            al[r] = __expf(m[r] - mn);
            m[r] = mn;
        }
        // per-lane tile sums (lambda-deferral: no shuffles here)
        float ts[4] = {0.f, 0.f, 0.f, 0.f};
#pragma unroll
        for (int cb = 0; cb < 4; cb++)
#pragma unroll
            for (int r = 0; r < 4; r++) {
                float p = __expf(s[cb][r] - m[r]);
                ts[r] += p;
                s[cb][r] = p;
            }
#pragma unroll
        for (int r = 0; r < 4; r++) {
            lam[r] = lam[r] * al[r] + ts[r];
            o[0][r] *= al[r]; o[1][r] *= al[r]; o[2][r] *= al[r]; o[3][r] *= al[r];
        }
        // P (C-layout) -> LDS -> A-operand layout; compiler orders write->read
#pragma unroll
        for (int cb = 0; cb < 4; cb++)
#pragma unroll
            for (int r = 0; r < 4; r++)
                pb[(quad * 4 + r) * 72 + cb * 16 + l16] = (short)f2b(s[cb][r]);
        bf16x8 pf0 = *(const bf16x8*)(pb + l16 * 72 + quad * 8);
        bf16x8 pf1 = *(const bf16x8*)(pb + l16 * 72 + 32 + quad * 8);
#pragma unroll
        for (int db = 0; db < 4; db++) {
            const unsigned short* vbase =
                vt + ((size_t)h * 64 + db * 16 + l16) * 4096 + kv0 + quad * 8;
            bf16x8 vf0 = *(const bf16x8*)(vbase);
            bf16x8 vf1 = *(const bf16x8*)(vbase + 32);
            o[db] = MFMA16(pf0, vf0, o[db]);
            o[db] = MFMA16(pf1, vf1, o[db]);
        }
    }

    // deferred row-sum reduction
#pragma unroll
    for (int r = 0; r < 4; r++)
#pragma unroll
        for (int off = 1; off < 16; off <<= 1)
            lam[r] += __shfl_xor(lam[r], off, 64);

    // -------- block-level merge of 4 KV-chunk partials
    __syncthreads();                       // all waves done with pbuf
    float* obuf = (float*)smem;            // [4 chunk][16 row][64 d]
    float* mlbuf = (float*)(smem + 16384); // [4 chunk][16 row][2]
#pragma unroll
    for (int db = 0; db < 4; db++)
#pragma unroll
        for (int r = 0; r < 4; r++)
            obuf[(wave * 16 + quad * 4 + r) * 64 + db * 16 + l16] = o[db][r];
    if (l16 == 0)
#pragma unroll
        for (int r = 0; r < 4; r++) {
            mlbuf[(wave * 16 + quad * 4 + r) * 2 + 0] = m[r];
            mlbuf[(wave * 16 + quad * 4 + r) * 2 + 1] = lam[r];
        }
    __syncthreads();

    int d = threadIdx.x & 63;
#pragma unroll
    for (int i = 0; i < 4; i++) {
        int row = (threadIdx.x >> 6) * 4 + i;
        float m0c = mlbuf[(0 * 16 + row) * 2], m1c = mlbuf[(1 * 16 + row) * 2];
        float m2c = mlbuf[(2 * 16 + row) * 2], m3c = mlbuf[(3 * 16 + row) * 2];
        float M = fmaxf(fmaxf(m0c, m1c), fmaxf(m2c, m3c));
        float e0 = __expf(m0c - M), e1 = __expf(m1c - M);
        float e2 = __expf(m2c - M), e3 = __expf(m3c - M);
        float L = mlbuf[(0 * 16 + row) * 2 + 1] * e0 + mlbuf[(1 * 16 + row) * 2 + 1] * e1
                + mlbuf[(2 * 16 + row) * 2 + 1] * e2 + mlbuf[(3 * 16 + row) * 2 + 1] * e3;
        float O = obuf[(0 * 16 + row) * 64 + d] * e0 + obuf[(1 * 16 + row) * 64 + d] * e1
                + obuf[(2 * 16 + row) * 64 + d] * e2 + obuf[(3 * 16 + row) * 64 + d] * e3;
        att[(size_t)(q0 + row) * 512 + h * 64 + d] = f2b(O / L);
    }
}

// ---------------------------------------------------------------- output GEMM (fp32 store)
__global__ __launch_bounds__(256) void out_gemm(
    const unsigned short* __restrict__ att, const unsigned short* __restrict__ w,
    const float* __restrict__ b, float* __restrict__ out) {
    int lane = threadIdx.x & 63, wave = threadIdx.x >> 6;
    int l16 = lane & 15, quad = lane >> 4;
    int m0 = blockIdx.y * 64 + wave * 16;
    int n0 = blockIdx.x * 64;

    const unsigned short* arow = att + (size_t)(m0 + l16) * 512 + quad * 8;
    f32x4 acc[4];
#pragma unroll
    for (int nb = 0; nb < 4; nb++) acc[nb] = (f32x4){0.f, 0.f, 0.f, 0.f};

    for (int k0 = 0; k0 < 512; k0 += 32) {
        bf16x8 af = *(const bf16x8*)(arow + k0);
#pragma unroll
        for (int nb = 0; nb < 4; nb++) {
            bf16x8 bf = *(const bf16x8*)(w + (size_t)(n0 + nb * 16 + l16) * 512 + k0 + quad * 8);
            acc[nb] = MFMA16(af, bf, acc[nb]);
        }
    }
#pragma unroll
    for (int nb = 0; nb < 4; nb++) {
        float bj = b[n0 + nb * 16 + l16];
#pragma unroll
        for (int r = 0; r < 4; r++)
            out[(size_t)(m0 + quad * 4 + r) * 512 + n0 + nb * 16 + l16] =
                acc[nb][r] + bj;
    }
}

extern "C" void kernel_launch(void* const* d_in, const int* in_sizes, int n_in,
                              void* d_out, int out_size, void* d_ws, size_t ws_size,
                              hipStream_t stream) {
    const float* x    = (const float*)d_in[0];
    const float* lat  = (const float*)d_in[1];
    const float* lon  = (const float*)d_in[2];
    const float* wqkv = (const float*)d_in[3];
    const float* bqkv = (const float*)d_in[4];
    const float* wout = (const float*)d_in[5];
    const float* bout = (const float*)d_in[6];
    float* out = (float*)d_out;

    char* ws = (char*)d_ws;
    float* dist        = (float*)ws;                                  // 64 MiB
    double* partials   = (double*)(ws + 67108864);                    // 64 KiB
    float* nis         = (float*)(ws + 67108864 + 65536);             // 64 B
    unsigned short* q  = (unsigned short*)(ws + 67108864 + 65600);
    unsigned short* k  = q  + (size_t)8 * 4096 * 64;   // 4 MiB each
    unsigned short* vt = k  + (size_t)8 * 4096 * 64;
    unsigned short* att = vt + (size_t)8 * 4096 * 64;
    unsigned short* xb  = att + (size_t)4096 * 512;
    unsigned short* wqb = xb  + (size_t)4096 * 512;
    unsigned short* wob = wqb + (size_t)1536 * 512;

    cvt_kernel<<<2048, 256, 0, stream>>>(x, xb, 4096 * 512);
    cvt_kernel<<<768, 256, 0, stream>>>(wqkv, wqb, 1536 * 512);
    cvt_kernel<<<256, 256, 0, stream>>>(wout, wob, 512 * 512);
    dist_kernel<<<4096, 256, 0, stream>>>(lat, lon, dist, partials);
    stats_kernel<<<1, 256, 0, stream>>>(partials, nis);
    qkv_gemm<<<dim3(24, 64), 256, 0, stream>>>(xb, wqb, bqkv, q, k, vt);
    attn_kernel<<<2048, 256, 0, stream>>>(q, k, vt, dist, nis, att);
    out_gemm<<<dim3(8, 64), 256, 0, stream>>>(att, wob, bout, out);
}

// Round 16
// 446.419 us; speedup vs baseline: 1.2892x; 1.0705x over previous
//
#include <hip/hip_runtime.h>
#include <hip/hip_bf16.h>

// SphericalAttention on MI355X (gfx950).  ROUND 16: R15 (green, 478us) + two
// memory-path fixes. (1) dist stored PERMUTED (col c -> (c&15)*4 + (c>>4)
// within each 64-block) so attn's bias load is one float4 per (r,iter)
// instead of 16 scalar dwords. (2) qkv_gemm V-epilogue stages the 64x64
// single-head tile in LDS (padded 64x72) and writes vt coalesced (the direct
// store scattered across ~64 cache lines per instruction).
// Inputs fp32; output fp32. N=4096, C=512, nh=8, dh=64.

typedef __attribute__((ext_vector_type(8))) short bf16x8;
typedef __attribute__((ext_vector_type(4))) float f32x4;

#define MFMA16(a, b, c) __builtin_amdgcn_mfma_f32_16x16x32_bf16(a, b, c, 0, 0, 0)

__device__ __forceinline__ unsigned short f2b(float f) {
    union { float f; unsigned int i; } v;
    v.f = f;
    unsigned int lsb = (v.i >> 16) & 1u;
    unsigned int r = v.i + 0x7fffu + lsb;   // RNE
    return (unsigned short)(r >> 16);
}

// ---------------------------------------------------------------- fp32 -> bf16
__global__ __launch_bounds__(256) void cvt_kernel(
    const float* __restrict__ in, unsigned short* __restrict__ out, int n) {
    int i = (blockIdx.x * 256 + threadIdx.x) * 4;
    if (i + 3 < n) {
        float4 v = *(const float4*)(in + i);
        ushort4 u;
        u.x = f2b(v.x); u.y = f2b(v.y); u.z = f2b(v.z); u.w = f2b(v.w);
        *(ushort4*)(out + i) = u;
    }
}

// ---------------------------------------------------------------- dist + stats
// dist is stored PERMUTED within each 64-column block: column c lands at
// (c&15)*4 + (c>>4), so attn lane l16 float4-loads cols {l16,16+l16,32+l16,48+l16}.
__global__ __launch_bounds__(256) void dist_kernel(
    const float* __restrict__ lat, const float* __restrict__ lon,
    float* __restrict__ dist, double* __restrict__ partials) {
    __shared__ float sl_i[64], sc_i[64], so_i[64];
    __shared__ float sl_j[64], sc_j[64], so_j[64];
    __shared__ double rs[256], rs2[256];

    int bi = blockIdx.x;
    int i0 = (bi >> 6) << 6;
    int j0 = (bi & 63) << 6;
    int tid = threadIdx.x;

    if (tid < 64) {
        float la = lat[i0 + tid];
        sl_i[tid] = la; sc_i[tid] = __cosf(la); so_i[tid] = lon[i0 + tid];
    } else if (tid < 128) {
        int t = tid - 64;
        float la = lat[j0 + t];
        sl_j[t] = la; sc_j[t] = __cosf(la); so_j[t] = lon[j0 + t];
    }
    __syncthreads();

    double s = 0.0, s2 = 0.0;
    int col = tid & 63;
    int pcol = ((col & 15) << 2) + (col >> 4);   // permuted position
    float latj = sl_j[col], cj = sc_j[col], lonj = so_j[col];
#pragma unroll
    for (int kk = 0; kk < 16; kk++) {
        int row = (kk << 2) + (tid >> 6);
        float dlat = latj - sl_i[row];
        float dlon = lonj - so_i[row];
        float h1 = __sinf(0.5f * dlat);
        float h2 = __sinf(0.5f * dlon);
        float a = h1 * h1 + sc_i[row] * cj * h2 * h2;
        a = fminf(fmaxf(a, 0.0f), 1.0f);
        float d = 2.0f * asinf(sqrtf(a));
        dist[(size_t)(i0 + row) * 4096 + j0 + pcol] = d;
        s += (double)d;
        s2 += (double)d * (double)d;
    }
    rs[tid] = s; rs2[tid] = s2;
    __syncthreads();
    for (int off = 128; off > 0; off >>= 1) {
        if (tid < off) { rs[tid] += rs[tid + off]; rs2[tid] += rs2[tid + off]; }
        __syncthreads();
    }
    if (tid == 0) {
        partials[2 * bi] = rs[0];
        partials[2 * bi + 1] = rs2[0];
    }
}

__global__ __launch_bounds__(256) void stats_kernel(
    const double* __restrict__ partials, float* __restrict__ neg_inv_std) {
    __shared__ double rs[256], rs2[256];
    int tid = threadIdx.x;
    double s = 0.0, s2 = 0.0;
    for (int i = tid; i < 4096; i += 256) {
        s += partials[2 * i];
        s2 += partials[2 * i + 1];
    }
    rs[tid] = s; rs2[tid] = s2;
    __syncthreads();
    for (int off = 128; off > 0; off >>= 1) {
        if (tid < off) { rs[tid] += rs[tid + off]; rs2[tid] += rs2[tid + off]; }
        __syncthreads();
    }
    if (tid == 0) {
        double n = 16777216.0;
        double mean = rs[0] / n;
        double var = (rs2[0] - n * mean * mean) / (n - 1.0);  // ddof=1
        *neg_inv_std = (float)(-1.0 / sqrt(var));
    }
}

// ---------------------------------------------------------------- QKV GEMM
// V-blocks (bx>=16) hold one full head's 64n x 64d tile: stage in LDS and
// write vt coalesced (n-contiguous) instead of the d-scatter.
__global__ __launch_bounds__(256) void qkv_gemm(
    const unsigned short* __restrict__ x, const unsigned short* __restrict__ w,
    const float* __restrict__ b,
    unsigned short* __restrict__ q, unsigned short* __restrict__ k,
    unsigned short* __restrict__ vt) {
    __shared__ unsigned short vstage[64][72];   // 9216 B; padded rows (16B-aligned)
    int lane = threadIdx.x & 63, wave = threadIdx.x >> 6;
    int l16 = lane & 15, quad = lane >> 4;
    int m0 = blockIdx.y * 64 + wave * 16;
    int n0 = blockIdx.x * 64;

    const unsigned short* arow = x + (size_t)(m0 + l16) * 512 + quad * 8;
    f32x4 acc[4];
#pragma unroll
    for (int nb = 0; nb < 4; nb++) acc[nb] = (f32x4){0.f, 0.f, 0.f, 0.f};

    for (int k0 = 0; k0 < 512; k0 += 32) {
        bf16x8 af = *(const bf16x8*)(arow + k0);
#pragma unroll
        for (int nb = 0; nb < 4; nb++) {
            bf16x8 bf = *(const bf16x8*)(w + (size_t)(n0 + nb * 16 + l16) * 512 + k0 + quad * 8);
            acc[nb] = MFMA16(af, bf, acc[nb]);
        }
    }
    if (blockIdx.x < 16) {                 // q / k blocks: direct store
#pragma unroll
        for (int nb = 0; nb < 4; nb++) {
            int j = n0 + nb * 16 + l16;
            float bj = b[j];
            int s = j >> 9;                // 0=q 1=k
            int rem = j & 511;
            int h = rem >> 6, d = rem & 63;
#pragma unroll
            for (int r = 0; r < 4; r++) {
                int n = m0 + quad * 4 + r;
                unsigned short u = f2b(acc[nb][r] + bj);
                if (s == 0) q[((size_t)h * 4096 + n) * 64 + d] = u;
                else        k[((size_t)h * 4096 + n) * 64 + d] = u;
            }
        }
    } else {                               // V block: one head, transpose via LDS
        int h = blockIdx.x - 16;
#pragma unroll
        for (int nb = 0; nb < 4; nb++) {
            int d = nb * 16 + l16;
            float bj = b[1024 + h * 64 + d];
#pragma unroll
            for (int r = 0; r < 4; r++)
                vstage[d][wave * 16 + quad * 4 + r] = f2b(acc[nb][r] + bj);
        }
        __syncthreads();
        int t = threadIdx.x;
        int d = t >> 2;                    // 0..63
        int nq = (t & 3) * 16;             // 0,16,32,48
        unsigned short* dst = vt + ((size_t)h * 64 + d) * 4096 + blockIdx.y * 64 + nq;
        const unsigned short* src = &vstage[d][nq];
        *(uint4*)dst = *(const uint4*)src;
        *(uint4*)(dst + 8) = *(const uint4*)(src + 8);
    }
}

// ---------------------------------------------------------------- flash attention
// Block = (head, 16 q-rows); 4 waves x 1024-wide KV quarters; online softmax
// with lambda-deferral; bias via one float4 load (permuted dist layout).
__global__ __launch_bounds__(256) void attn_kernel(
    const unsigned short* __restrict__ q, const unsigned short* __restrict__ k,
    const unsigned short* __restrict__ vt, const float* __restrict__ dist,
    const float* __restrict__ nis_p, unsigned short* __restrict__ att) {
    __shared__ __align__(16) char smem[16896];   // pbuf 4x(16x72)u16 | obuf+mlbuf
    int lane = threadIdx.x & 63, wave = threadIdx.x >> 6;
    int l16 = lane & 15, quad = lane >> 4;
    int h = blockIdx.x >> 8;
    int q0 = (blockIdx.x & 255) * 16;
    int kvbase = wave * 1024;
    float nis = *nis_p;
    const float scale = 0.125f;

    short* pb = (short*)smem + wave * 1152;   // 16 x 72

    const unsigned short* qbase = q + ((size_t)h * 4096 + q0 + l16) * 64 + quad * 8;
    bf16x8 qf0 = *(const bf16x8*)(qbase);
    bf16x8 qf1 = *(const bf16x8*)(qbase + 32);

    f32x4 o[4];
    float m[4], lam[4];
#pragma unroll
    for (int r = 0; r < 4; r++) {
        m[r] = -1e30f; lam[r] = 0.f;
        o[0][r] = 0.f; o[1][r] = 0.f; o[2][r] = 0.f; o[3][r] = 0.f;
    }

    for (int kv0 = kvbase; kv0 < kvbase + 1024; kv0 += 64) {
        f32x4 s[4];
#pragma unroll
        for (int cb = 0; cb < 4; cb++) {
            const unsigned short* kbase =
                k + ((size_t)h * 4096 + kv0 + cb * 16 + l16) * 64 + quad * 8;
            bf16x8 kf0 = *(const bf16x8*)(kbase);
            bf16x8 kf1 = *(const bf16x8*)(kbase + 32);
            f32x4 z = (f32x4){0.f, 0.f, 0.f, 0.f};
            z = MFMA16(qf0, kf0, z);
            z = MFMA16(qf1, kf1, z);
            s[cb] = z;
        }
        // bias: one float4 per r (permuted dist: .x->cb0 .y->cb1 .z->cb2 .w->cb3)
#pragma unroll
        for (int r = 0; r < 4; r++) {
            float4 dv = *(const float4*)(dist +
                (size_t)(q0 + quad * 4 + r) * 4096 + kv0 + l16 * 4);
            s[0][r] = s[0][r] * scale + dv.x * nis;
            s[1][r] = s[1][r] * scale + dv.y * nis;
            s[2][r] = s[2][r] * scale + dv.z * nis;
            s[3][r] = s[3][r] * scale + dv.w * nis;
        }
        // row max
        float mt[4];
#pragma unroll
        for (int r = 0; r < 4; r++) {
            float v = fmaxf(fmaxf(s[0][r], s[1][r]), fmaxf(s[2][r], s[3][r]));
#pragma unroll
            for (int off = 1; off < 16; off <<= 1)
                v = fmaxf(v, __shfl_xor(v, off, 64));
            mt[r] = v;
        }
        float al[4];
#pragma unroll
        for (int r = 0; r < 4; r++) {
            float mn = fmaxf(m[r], mt[r]);
            al[r] = __expf(m[r] - mn);
            m[r] = mn;
        }
        // per-lane tile sums (lambda-deferral: no shuffles here)
        float ts[4] = {0.f, 0.f, 0.f, 0.f};
#pragma unroll
        for (int cb = 0; cb < 4; cb++)
#pragma unroll
            for (int r = 0; r < 4; r++) {
                float p = __expf(s[cb][r] - m[r]);
                ts[r] += p;
                s[cb][r] = p;
            }
#pragma unroll
        for (int r = 0; r < 4; r++) {
            lam[r] = lam[r] * al[r] + ts[r];
            o[0][r] *= al[r]; o[1][r] *= al[r]; o[2][r] *= al[r]; o[3][r] *= al[r];
        }
        // P (C-layout) -> LDS -> A-operand layout
#pragma unroll
        for (int cb = 0; cb < 4; cb++)
#pragma unroll
            for (int r = 0; r < 4; r++)
                pb[(quad * 4 + r) * 72 + cb * 16 + l16] = (short)f2b(s[cb][r]);
        bf16x8 pf0 = *(const bf16x8*)(pb + l16 * 72 + quad * 8);
        bf16x8 pf1 = *(const bf16x8*)(pb + l16 * 72 + 32 + quad * 8);
#pragma unroll
        for (int db = 0; db < 4; db++) {
            const unsigned short* vbase =
                vt + ((size_t)h * 64 + db * 16 + l16) * 4096 + kv0 + quad * 8;
            bf16x8 vf0 = *(const bf16x8*)(vbase);
            bf16x8 vf1 = *(const bf16x8*)(vbase + 32);
            o[db] = MFMA16(pf0, vf0, o[db]);
            o[db] = MFMA16(pf1, vf1, o[db]);
        }
    }

    // deferred row-sum reduction
#pragma unroll
    for (int r = 0; r < 4; r++)
#pragma unroll
        for (int off = 1; off < 16; off <<= 1)
            lam[r] += __shfl_xor(lam[r], off, 64);

    // -------- block-level merge of 4 KV-chunk partials
    __syncthreads();                       // all waves done with pbuf
    float* obuf = (float*)smem;            // [4 chunk][16 row][64 d]
    float* mlbuf = (float*)(smem + 16384); // [4 chunk][16 row][2]
#pragma unroll
    for (int db = 0; db < 4; db++)
#pragma unroll
        for (int r = 0; r < 4; r++)
            obuf[(wave * 16 + quad * 4 + r) * 64 + db * 16 + l16] = o[db][r];
    if (l16 == 0)
#pragma unroll
        for (int r = 0; r < 4; r++) {
            mlbuf[(wave * 16 + quad * 4 + r) * 2 + 0] = m[r];
            mlbuf[(wave * 16 + quad * 4 + r) * 2 + 1] = lam[r];
        }
    __syncthreads();

    int d = threadIdx.x & 63;
#pragma unroll
    for (int i = 0; i < 4; i++) {
        int row = (threadIdx.x >> 6) * 4 + i;
        float m0c = mlbuf[(0 * 16 + row) * 2], m1c = mlbuf[(1 * 16 + row) * 2];
        float m2c = mlbuf[(2 * 16 + row) * 2], m3c = mlbuf[(3 * 16 + row) * 2];
        float M = fmaxf(fmaxf(m0c, m1c), fmaxf(m2c, m3c));
        float e0 = __expf(m0c - M), e1 = __expf(m1c - M);
        float e2 = __expf(m2c - M), e3 = __expf(m3c - M);
        float L = mlbuf[(0 * 16 + row) * 2 + 1] * e0 + mlbuf[(1 * 16 + row) * 2 + 1] * e1
                + mlbuf[(2 * 16 + row) * 2 + 1] * e2 + mlbuf[(3 * 16 + row) * 2 + 1] * e3;
        float O = obuf[(0 * 16 + row) * 64 + d] * e0 + obuf[(1 * 16 + row) * 64 + d] * e1
                + obuf[(2 * 16 + row) * 64 + d] * e2 + obuf[(3 * 16 + row) * 64 + d] * e3;
        att[(size_t)(q0 + row) * 512 + h * 64 + d] = f2b(O / L);
    }
}

// ---------------------------------------------------------------- output GEMM (fp32 store)
__global__ __launch_bounds__(256) void out_gemm(
    const unsigned short* __restrict__ att, const unsigned short* __restrict__ w,
    const float* __restrict__ b, float* __restrict__ out) {
    int lane = threadIdx.x & 63, wave = threadIdx.x >> 6;
    int l16 = lane & 15, quad = lane >> 4;
    int m0 = blockIdx.y * 64 + wave * 16;
    int n0 = blockIdx.x * 64;

    const unsigned short* arow = att + (size_t)(m0 + l16) * 512 + quad * 8;
    f32x4 acc[4];
#pragma unroll
    for (int nb = 0; nb < 4; nb++) acc[nb] = (f32x4){0.f, 0.f, 0.f, 0.f};

    for (int k0 = 0; k0 < 512; k0 += 32) {
        bf16x8 af = *(const bf16x8*)(arow + k0);
#pragma unroll
        for (int nb = 0; nb < 4; nb++) {
            bf16x8 bf = *(const bf16x8*)(w + (size_t)(n0 + nb * 16 + l16) * 512 + k0 + quad * 8);
            acc[nb] = MFMA16(af, bf, acc[nb]);
        }
    }
#pragma unroll
    for (int nb = 0; nb < 4; nb++) {
        float bj = b[n0 + nb * 16 + l16];
#pragma unroll
        for (int r = 0; r < 4; r++)
            out[(size_t)(m0 + quad * 4 + r) * 512 + n0 + nb * 16 + l16] =
                acc[nb][r] + bj;
    }
}

extern "C" void kernel_launch(void* const* d_in, const int* in_sizes, int n_in,
                              void* d_out, int out_size, void* d_ws, size_t ws_size,
                              hipStream_t stream) {
    const float* x    = (const float*)d_in[0];
    const float* lat  = (const float*)d_in[1];
    const float* lon  = (const float*)d_in[2];
    const float* wqkv = (const float*)d_in[3];
    const float* bqkv = (const float*)d_in[4];
    const float* wout = (const float*)d_in[5];
    const float* bout = (const float*)d_in[6];
    float* out = (float*)d_out;

    char* ws = (char*)d_ws;
    float* dist        = (float*)ws;                                  // 64 MiB
    double* partials   = (double*)(ws + 67108864);                    // 64 KiB
    float* nis         = (float*)(ws + 67108864 + 65536);             // 64 B
    unsigned short* q  = (unsigned short*)(ws + 67108864 + 65600);
    unsigned short* k  = q  + (size_t)8 * 4096 * 64;   // 4 MiB each
    unsigned short* vt = k  + (size_t)8 * 4096 * 64;
    unsigned short* att = vt + (size_t)8 * 4096 * 64;
    unsigned short* xb  = att + (size_t)4096 * 512;
    unsigned short* wqb = xb  + (size_t)4096 * 512;
    unsigned short* wob = wqb + (size_t)1536 * 512;

    cvt_kernel<<<2048, 256, 0, stream>>>(x, xb, 4096 * 512);
    cvt_kernel<<<768, 256, 0, stream>>>(wqkv, wqb, 1536 * 512);
    cvt_kernel<<<256, 256, 0, stream>>>(wout, wob, 512 * 512);
    dist_kernel<<<4096, 256, 0, stream>>>(lat, lon, dist, partials);
    stats_kernel<<<1, 256, 0, stream>>>(partials, nis);
    qkv_gemm<<<dim3(24, 64), 256, 0, stream>>>(xb, wqb, bqkv, q, k, vt);
    attn_kernel<<<2048, 256, 0, stream>>>(q, k, vt, dist, nis, att);
    out_gemm<<<dim3(8, 64), 256, 0, stream>>>(att, wob, bout, out);
}

// Round 17
// 427.109 us; speedup vs baseline: 1.3475x; 1.0452x over previous
//
#include <hip/hip_runtime.h>
#include <hip/hip_bf16.h>

// SphericalAttention on MI355X (gfx950).  ROUND 17: R16 (green, 446us) + one
// change: attn gets __launch_bounds__(256, 4). R16's float4-bias code pushed
// arch VGPR to 68 (+64 acc = 132 > 128-reg boundary) -> occupancy fell
// 46.5->28.6%. Budget 128 (=512/4 waves) is known feasible (R15 fit in
// 60+64=124), so forcing it restores 4 waves/SIMD without spilling.
// (Not R8's mistake: that was (256,8) -> 64-reg budget, guaranteed spills.)
// Inputs fp32; output fp32. N=4096, C=512, nh=8, dh=64.

typedef __attribute__((ext_vector_type(8))) short bf16x8;
typedef __attribute__((ext_vector_type(4))) float f32x4;

#define MFMA16(a, b, c) __builtin_amdgcn_mfma_f32_16x16x32_bf16(a, b, c, 0, 0, 0)

__device__ __forceinline__ unsigned short f2b(float f) {
    union { float f; unsigned int i; } v;
    v.f = f;
    unsigned int lsb = (v.i >> 16) & 1u;
    unsigned int r = v.i + 0x7fffu + lsb;   // RNE
    return (unsigned short)(r >> 16);
}

// ---------------------------------------------------------------- fp32 -> bf16
__global__ __launch_bounds__(256) void cvt_kernel(
    const float* __restrict__ in, unsigned short* __restrict__ out, int n) {
    int i = (blockIdx.x * 256 + threadIdx.x) * 4;
    if (i + 3 < n) {
        float4 v = *(const float4*)(in + i);
        ushort4 u;
        u.x = f2b(v.x); u.y = f2b(v.y); u.z = f2b(v.z); u.w = f2b(v.w);
        *(ushort4*)(out + i) = u;
    }
}

// ---------------------------------------------------------------- dist + stats
// dist stored PERMUTED within each 64-column block: col c -> (c&15)*4 + (c>>4),
// so attn lane l16 float4-loads cols {l16,16+l16,32+l16,48+l16}.
__global__ __launch_bounds__(256) void dist_kernel(
    const float* __restrict__ lat, const float* __restrict__ lon,
    float* __restrict__ dist, double* __restrict__ partials) {
    __shared__ float sl_i[64], sc_i[64], so_i[64];
    __shared__ float sl_j[64], sc_j[64], so_j[64];
    __shared__ double rs[256], rs2[256];

    int bi = blockIdx.x;
    int i0 = (bi >> 6) << 6;
    int j0 = (bi & 63) << 6;
    int tid = threadIdx.x;

    if (tid < 64) {
        float la = lat[i0 + tid];
        sl_i[tid] = la; sc_i[tid] = __cosf(la); so_i[tid] = lon[i0 + tid];
    } else if (tid < 128) {
        int t = tid - 64;
        float la = lat[j0 + t];
        sl_j[t] = la; sc_j[t] = __cosf(la); so_j[t] = lon[j0 + t];
    }
    __syncthreads();

    double s = 0.0, s2 = 0.0;
    int col = tid & 63;
    int pcol = ((col & 15) << 2) + (col >> 4);   // permuted position
    float latj = sl_j[col], cj = sc_j[col], lonj = so_j[col];
#pragma unroll
    for (int kk = 0; kk < 16; kk++) {
        int row = (kk << 2) + (tid >> 6);
        float dlat = latj - sl_i[row];
        float dlon = lonj - so_i[row];
        float h1 = __sinf(0.5f * dlat);
        float h2 = __sinf(0.5f * dlon);
        float a = h1 * h1 + sc_i[row] * cj * h2 * h2;
        a = fminf(fmaxf(a, 0.0f), 1.0f);
        float d = 2.0f * asinf(sqrtf(a));
        dist[(size_t)(i0 + row) * 4096 + j0 + pcol] = d;
        s += (double)d;
        s2 += (double)d * (double)d;
    }
    rs[tid] = s; rs2[tid] = s2;
    __syncthreads();
    for (int off = 128; off > 0; off >>= 1) {
        if (tid < off) { rs[tid] += rs[tid + off]; rs2[tid] += rs2[tid + off]; }
        __syncthreads();
    }
    if (tid == 0) {
        partials[2 * bi] = rs[0];
        partials[2 * bi + 1] = rs2[0];
    }
}

__global__ __launch_bounds__(256) void stats_kernel(
    const double* __restrict__ partials, float* __restrict__ neg_inv_std) {
    __shared__ double rs[256], rs2[256];
    int tid = threadIdx.x;
    double s = 0.0, s2 = 0.0;
    for (int i = tid; i < 4096; i += 256) {
        s += partials[2 * i];
        s2 += partials[2 * i + 1];
    }
    rs[tid] = s; rs2[tid] = s2;
    __syncthreads();
    for (int off = 128; off > 0; off >>= 1) {
        if (tid < off) { rs[tid] += rs[tid + off]; rs2[tid] += rs2[tid + off]; }
        __syncthreads();
    }
    if (tid == 0) {
        double n = 16777216.0;
        double mean = rs[0] / n;
        double var = (rs2[0] - n * mean * mean) / (n - 1.0);  // ddof=1
        *neg_inv_std = (float)(-1.0 / sqrt(var));
    }
}

// ---------------------------------------------------------------- QKV GEMM
// V-blocks (bx>=16) hold one full head's 64n x 64d tile: stage in LDS and
// write vt coalesced (n-contiguous) instead of the d-scatter.
__global__ __launch_bounds__(256) void qkv_gemm(
    const unsigned short* __restrict__ x, const unsigned short* __restrict__ w,
    const float* __restrict__ b,
    unsigned short* __restrict__ q, unsigned short* __restrict__ k,
    unsigned short* __restrict__ vt) {
    __shared__ unsigned short vstage[64][72];   // 9216 B; padded rows (16B-aligned)
    int lane = threadIdx.x & 63, wave = threadIdx.x >> 6;
    int l16 = lane & 15, quad = lane >> 4;
    int m0 = blockIdx.y * 64 + wave * 16;
    int n0 = blockIdx.x * 64;

    const unsigned short* arow = x + (size_t)(m0 + l16) * 512 + quad * 8;
    f32x4 acc[4];
#pragma unroll
    for (int nb = 0; nb < 4; nb++) acc[nb] = (f32x4){0.f, 0.f, 0.f, 0.f};

    for (int k0 = 0; k0 < 512; k0 += 32) {
        bf16x8 af = *(const bf16x8*)(arow + k0);
#pragma unroll
        for (int nb = 0; nb < 4; nb++) {
            bf16x8 bf = *(const bf16x8*)(w + (size_t)(n0 + nb * 16 + l16) * 512 + k0 + quad * 8);
            acc[nb] = MFMA16(af, bf, acc[nb]);
        }
    }
    if (blockIdx.x < 16) {                 // q / k blocks: direct store
#pragma unroll
        for (int nb = 0; nb < 4; nb++) {
            int j = n0 + nb * 16 + l16;
            float bj = b[j];
            int s = j >> 9;                // 0=q 1=k
            int rem = j & 511;
            int h = rem >> 6, d = rem & 63;
#pragma unroll
            for (int r = 0; r < 4; r++) {
                int n = m0 + quad * 4 + r;
                unsigned short u = f2b(acc[nb][r] + bj);
                if (s == 0) q[((size_t)h * 4096 + n) * 64 + d] = u;
                else        k[((size_t)h * 4096 + n) * 64 + d] = u;
            }
        }
    } else {                               // V block: one head, transpose via LDS
        int h = blockIdx.x - 16;
#pragma unroll
        for (int nb = 0; nb < 4; nb++) {
            int d = nb * 16 + l16;
            float bj = b[1024 + h * 64 + d];
#pragma unroll
            for (int r = 0; r < 4; r++)
                vstage[d][wave * 16 + quad * 4 + r] = f2b(acc[nb][r] + bj);
        }
        __syncthreads();
        int t = threadIdx.x;
        int d = t >> 2;                    // 0..63
        int nq = (t & 3) * 16;             // 0,16,32,48
        unsigned short* dst = vt + ((size_t)h * 64 + d) * 4096 + blockIdx.y * 64 + nq;
        const unsigned short* src = &vstage[d][nq];
        *(uint4*)dst = *(const uint4*)src;
        *(uint4*)(dst + 8) = *(const uint4*)(src + 8);
    }
}

// ---------------------------------------------------------------- flash attention
// Block = (head, 16 q-rows); 4 waves x 1024-wide KV quarters; online softmax
// with lambda-deferral; float4 bias loads (permuted dist). launch_bounds
// (256,4) pins the 128-reg budget -> 4 waves/SIMD.
__global__ __launch_bounds__(256, 4) void attn_kernel(
    const unsigned short* __restrict__ q, const unsigned short* __restrict__ k,
    const unsigned short* __restrict__ vt, const float* __restrict__ dist,
    const float* __restrict__ nis_p, unsigned short* __restrict__ att) {
    __shared__ __align__(16) char smem[16896];   // pbuf 4x(16x72)u16 | obuf+mlbuf
    int lane = threadIdx.x & 63, wave = threadIdx.x >> 6;
    int l16 = lane & 15, quad = lane >> 4;
    int h = blockIdx.x >> 8;
    int q0 = (blockIdx.x & 255) * 16;
    int kvbase = wave * 1024;
    float nis = *nis_p;
    const float scale = 0.125f;

    short* pb = (short*)smem + wave * 1152;   // 16 x 72

    const unsigned short* qbase = q + ((size_t)h * 4096 + q0 + l16) * 64 + quad * 8;
    bf16x8 qf0 = *(const bf16x8*)(qbase);
    bf16x8 qf1 = *(const bf16x8*)(qbase + 32);

    f32x4 o[4];
    float m[4], lam[4];
#pragma unroll
    for (int r = 0; r < 4; r++) {
        m[r] = -1e30f; lam[r] = 0.f;
        o[0][r] = 0.f; o[1][r] = 0.f; o[2][r] = 0.f; o[3][r] = 0.f;
    }

    for (int kv0 = kvbase; kv0 < kvbase + 1024; kv0 += 64) {
        f32x4 s[4];
#pragma unroll
        for (int cb = 0; cb < 4; cb++) {
            const unsigned short* kbase =
                k + ((size_t)h * 4096 + kv0 + cb * 16 + l16) * 64 + quad * 8;
            bf16x8 kf0 = *(const bf16x8*)(kbase);
            bf16x8 kf1 = *(const bf16x8*)(kbase + 32);
            f32x4 z = (f32x4){0.f, 0.f, 0.f, 0.f};
            z = MFMA16(qf0, kf0, z);
            z = MFMA16(qf1, kf1, z);
            s[cb] = z;
        }
        // bias: one float4 per r (permuted dist: .x->cb0 .y->cb1 .z->cb2 .w->cb3)
#pragma unroll
        for (int r = 0; r < 4; r++) {
            float4 dv = *(const float4*)(dist +
                (size_t)(q0 + quad * 4 + r) * 4096 + kv0 + l16 * 4);
            s[0][r] = s[0][r] * scale + dv.x * nis;
            s[1][r] = s[1][r] * scale + dv.y * nis;
            s[2][r] = s[2][r] * scale + dv.z * nis;
            s[3][r] = s[3][r] * scale + dv.w * nis;
        }
        // row max
        float mt[4];
#pragma unroll
        for (int r = 0; r < 4; r++) {
            float v = fmaxf(fmaxf(s[0][r], s[1][r]), fmaxf(s[2][r], s[3][r]));
#pragma unroll
            for (int off = 1; off < 16; off <<= 1)
                v = fmaxf(v, __shfl_xor(v, off, 64));
            mt[r] = v;
        }
        float al[4];
#pragma unroll
        for (int r = 0; r < 4; r++) {
            float mn = fmaxf(m[r], mt[r]);
            al[r] = __expf(m[r] - mn);
            m[r] = mn;
        }
        // per-lane tile sums (lambda-deferral: no shuffles here)
        float ts[4] = {0.f, 0.f, 0.f, 0.f};
#pragma unroll
        for (int cb = 0; cb < 4; cb++)
#pragma unroll
            for (int r = 0; r < 4; r++) {
                float p = __expf(s[cb][r] - m[r]);
                ts[r] += p;
                s[cb][r] = p;
            }
#pragma unroll
        for (int r = 0; r < 4; r++) {
            lam[r] = lam[r] * al[r] + ts[r];
            o[0][r] *= al[r]; o[1][r] *= al[r]; o[2][r] *= al[r]; o[3][r] *= al[r];
        }
        // P (C-layout) -> LDS -> A-operand layout
#pragma unroll
        for (int cb = 0; cb < 4; cb++)
#pragma unroll
            for (int r = 0; r < 4; r++)
                pb[(quad * 4 + r) * 72 + cb * 16 + l16] = (short)f2b(s[cb][r]);
        bf16x8 pf0 = *(const bf16x8*)(pb + l16 * 72 + quad * 8);
        bf16x8 pf1 = *(const bf16x8*)(pb + l16 * 72 + 32 + quad * 8);
#pragma unroll
        for (int db = 0; db < 4; db++) {
            const unsigned short* vbase =
                vt + ((size_t)h * 64 + db * 16 + l16) * 4096 + kv0 + quad * 8;
            bf16x8 vf0 = *(const bf16x8*)(vbase);
            bf16x8 vf1 = *(const bf16x8*)(vbase + 32);
            o[db] = MFMA16(pf0, vf0, o[db]);
            o[db] = MFMA16(pf1, vf1, o[db]);
        }
    }

    // deferred row-sum reduction
#pragma unroll
    for (int r = 0; r < 4; r++)
#pragma unroll
        for (int off = 1; off < 16; off <<= 1)
            lam[r] += __shfl_xor(lam[r], off, 64);

    // -------- block-level merge of 4 KV-chunk partials
    __syncthreads();                       // all waves done with pbuf
    float* obuf = (float*)smem;            // [4 chunk][16 row][64 d]
    float* mlbuf = (float*)(smem + 16384); // [4 chunk][16 row][2]
#pragma unroll
    for (int db = 0; db < 4; db++)
#pragma unroll
        for (int r = 0; r < 4; r++)
            obuf[(wave * 16 + quad * 4 + r) * 64 + db * 16 + l16] = o[db][r];
    if (l16 == 0)
#pragma unroll
        for (int r = 0; r < 4; r++) {
            mlbuf[(wave * 16 + quad * 4 + r) * 2 + 0] = m[r];
            mlbuf[(wave * 16 + quad * 4 + r) * 2 + 1] = lam[r];
        }
    __syncthreads();

    int d = threadIdx.x & 63;
#pragma unroll
    for (int i = 0; i < 4; i++) {
        int row = (threadIdx.x >> 6) * 4 + i;
        float m0c = mlbuf[(0 * 16 + row) * 2], m1c = mlbuf[(1 * 16 + row) * 2];
        float m2c = mlbuf[(2 * 16 + row) * 2], m3c = mlbuf[(3 * 16 + row) * 2];
        float M = fmaxf(fmaxf(m0c, m1c), fmaxf(m2c, m3c));
        float e0 = __expf(m0c - M), e1 = __expf(m1c - M);
        float e2 = __expf(m2c - M), e3 = __expf(m3c - M);
        float L = mlbuf[(0 * 16 + row) * 2 + 1] * e0 + mlbuf[(1 * 16 + row) * 2 + 1] * e1
                + mlbuf[(2 * 16 + row) * 2 + 1] * e2 + mlbuf[(3 * 16 + row) * 2 + 1] * e3;
        float O = obuf[(0 * 16 + row) * 64 + d] * e0 + obuf[(1 * 16 + row) * 64 + d] * e1
                + obuf[(2 * 16 + row) * 64 + d] * e2 + obuf[(3 * 16 + row) * 64 + d] * e3;
        att[(size_t)(q0 + row) * 512 + h * 64 + d] = f2b(O / L);
    }
}

// ---------------------------------------------------------------- output GEMM (fp32 store)
__global__ __launch_bounds__(256) void out_gemm(
    const unsigned short* __restrict__ att, const unsigned short* __restrict__ w,
    const float* __restrict__ b, float* __restrict__ out) {
    int lane = threadIdx.x & 63, wave = threadIdx.x >> 6;
    int l16 = lane & 15, quad = lane >> 4;
    int m0 = blockIdx.y * 64 + wave * 16;
    int n0 = blockIdx.x * 64;

    const unsigned short* arow = att + (size_t)(m0 + l16) * 512 + quad * 8;
    f32x4 acc[4];
#pragma unroll
    for (int nb = 0; nb < 4; nb++) acc[nb] = (f32x4){0.f, 0.f, 0.f, 0.f};

    for (int k0 = 0; k0 < 512; k0 += 32) {
        bf16x8 af = *(const bf16x8*)(arow + k0);
#pragma unroll
        for (int nb = 0; nb < 4; nb++) {
            bf16x8 bf = *(const bf16x8*)(w + (size_t)(n0 + nb * 16 + l16) * 512 + k0 + quad * 8);
            acc[nb] = MFMA16(af, bf, acc[nb]);
        }
    }
#pragma unroll
    for (int nb = 0; nb < 4; nb++) {
        float bj = b[n0 + nb * 16 + l16];
#pragma unroll
        for (int r = 0; r < 4; r++)
            out[(size_t)(m0 + quad * 4 + r) * 512 + n0 + nb * 16 + l16] =
                acc[nb][r] + bj;
    }
}

extern "C" void kernel_launch(void* const* d_in, const int* in_sizes, int n_in,
                              void* d_out, int out_size, void* d_ws, size_t ws_size,
                              hipStream_t stream) {
    const float* x    = (const float*)d_in[0];
    const float* lat  = (const float*)d_in[1];
    const float* lon  = (const float*)d_in[2];
    const float* wqkv = (const float*)d_in[3];
    const float* bqkv = (const float*)d_in[4];
    const float* wout = (const float*)d_in[5];
    const float* bout = (const float*)d_in[6];
    float* out = (float*)d_out;

    char* ws = (char*)d_ws;
    float* dist        = (float*)ws;                                  // 64 MiB
    double* partials   = (double*)(ws + 67108864);                    // 64 KiB
    float* nis         = (float*)(ws + 67108864 + 65536);             // 64 B
    unsigned short* q  = (unsigned short*)(ws + 67108864 + 65600);
    unsigned short* k  = q  + (size_t)8 * 4096 * 64;   // 4 MiB each
    unsigned short* vt = k  + (size_t)8 * 4096 * 64;
    unsigned short* att = vt + (size_t)8 * 4096 * 64;
    unsigned short* xb  = att + (size_t)4096 * 512;
    unsigned short* wqb = xb  + (size_t)4096 * 512;
    unsigned short* wob = wqb + (size_t)1536 * 512;

    cvt_kernel<<<2048, 256, 0, stream>>>(x, xb, 4096 * 512);
    cvt_kernel<<<768, 256, 0, stream>>>(wqkv, wqb, 1536 * 512);
    cvt_kernel<<<256, 256, 0, stream>>>(wout, wob, 512 * 512);
    dist_kernel<<<4096, 256, 0, stream>>>(lat, lon, dist, partials);
    stats_kernel<<<1, 256, 0, stream>>>(partials, nis);
    qkv_gemm<<<dim3(24, 64), 256, 0, stream>>>(xb, wqb, bqkv, q, k, vt);
    attn_kernel<<<2048, 256, 0, stream>>>(q, k, vt, dist, nis, att);
    out_gemm<<<dim3(8, 64), 256, 0, stream>>>(att, wob, bout, out);
}

// Round 18
// 426.527 us; speedup vs baseline: 1.3493x; 1.0014x over previous
//
#include <hip/hip_runtime.h>
#include <hip/hip_bf16.h>

// SphericalAttention on MI355X (gfx950).  ROUND 18: R17 (green, 427us) + one
// change: attn block order q-group-major (h = blockIdx&7, q0 = blockIdx>>3).
// Head-major order re-read each 64MB dist row-slice 8x at widely separated
// times (FETCH 216MB, L3/HBM-latency bias loads on the softmax critical
// path). Swizzled, the 8 heads of a q-group are dispatch-adjacent: dist rows
// L3-hit after one fill, and with round-robin XCD assignment head h pins to
// XCD h so each XCD L2 keeps its head's K/V hot.
// Inputs fp32; output fp32. N=4096, C=512, nh=8, dh=64.

typedef __attribute__((ext_vector_type(8))) short bf16x8;
typedef __attribute__((ext_vector_type(4))) float f32x4;

#define MFMA16(a, b, c) __builtin_amdgcn_mfma_f32_16x16x32_bf16(a, b, c, 0, 0, 0)

__device__ __forceinline__ unsigned short f2b(float f) {
    union { float f; unsigned int i; } v;
    v.f = f;
    unsigned int lsb = (v.i >> 16) & 1u;
    unsigned int r = v.i + 0x7fffu + lsb;   // RNE
    return (unsigned short)(r >> 16);
}

// ---------------------------------------------------------------- fp32 -> bf16
__global__ __launch_bounds__(256) void cvt_kernel(
    const float* __restrict__ in, unsigned short* __restrict__ out, int n) {
    int i = (blockIdx.x * 256 + threadIdx.x) * 4;
    if (i + 3 < n) {
        float4 v = *(const float4*)(in + i);
        ushort4 u;
        u.x = f2b(v.x); u.y = f2b(v.y); u.z = f2b(v.z); u.w = f2b(v.w);
        *(ushort4*)(out + i) = u;
    }
}

// ---------------------------------------------------------------- dist + stats
// dist stored PERMUTED within each 64-column block: col c -> (c&15)*4 + (c>>4),
// so attn lane l16 float4-loads cols {l16,16+l16,32+l16,48+l16}.
__global__ __launch_bounds__(256) void dist_kernel(
    const float* __restrict__ lat, const float* __restrict__ lon,
    float* __restrict__ dist, double* __restrict__ partials) {
    __shared__ float sl_i[64], sc_i[64], so_i[64];
    __shared__ float sl_j[64], sc_j[64], so_j[64];
    __shared__ double rs[256], rs2[256];

    int bi = blockIdx.x;
    int i0 = (bi >> 6) << 6;
    int j0 = (bi & 63) << 6;
    int tid = threadIdx.x;

    if (tid < 64) {
        float la = lat[i0 + tid];
        sl_i[tid] = la; sc_i[tid] = __cosf(la); so_i[tid] = lon[i0 + tid];
    } else if (tid < 128) {
        int t = tid - 64;
        float la = lat[j0 + t];
        sl_j[t] = la; sc_j[t] = __cosf(la); so_j[t] = lon[j0 + t];
    }
    __syncthreads();

    double s = 0.0, s2 = 0.0;
    int col = tid & 63;
    int pcol = ((col & 15) << 2) + (col >> 4);   // permuted position
    float latj = sl_j[col], cj = sc_j[col], lonj = so_j[col];
#pragma unroll
    for (int kk = 0; kk < 16; kk++) {
        int row = (kk << 2) + (tid >> 6);
        float dlat = latj - sl_i[row];
        float dlon = lonj - so_i[row];
        float h1 = __sinf(0.5f * dlat);
        float h2 = __sinf(0.5f * dlon);
        float a = h1 * h1 + sc_i[row] * cj * h2 * h2;
        a = fminf(fmaxf(a, 0.0f), 1.0f);
        float d = 2.0f * asinf(sqrtf(a));
        dist[(size_t)(i0 + row) * 4096 + j0 + pcol] = d;
        s += (double)d;
        s2 += (double)d * (double)d;
    }
    rs[tid] = s; rs2[tid] = s2;
    __syncthreads();
    for (int off = 128; off > 0; off >>= 1) {
        if (tid < off) { rs[tid] += rs[tid + off]; rs2[tid] += rs2[tid + off]; }
        __syncthreads();
    }
    if (tid == 0) {
        partials[2 * bi] = rs[0];
        partials[2 * bi + 1] = rs2[0];
    }
}

__global__ __launch_bounds__(256) void stats_kernel(
    const double* __restrict__ partials, float* __restrict__ neg_inv_std) {
    __shared__ double rs[256], rs2[256];
    int tid = threadIdx.x;
    double s = 0.0, s2 = 0.0;
    for (int i = tid; i < 4096; i += 256) {
        s += partials[2 * i];
        s2 += partials[2 * i + 1];
    }
    rs[tid] = s; rs2[tid] = s2;
    __syncthreads();
    for (int off = 128; off > 0; off >>= 1) {
        if (tid < off) { rs[tid] += rs[tid + off]; rs2[tid] += rs2[tid + off]; }
        __syncthreads();
    }
    if (tid == 0) {
        double n = 16777216.0;
        double mean = rs[0] / n;
        double var = (rs2[0] - n * mean * mean) / (n - 1.0);  // ddof=1
        *neg_inv_std = (float)(-1.0 / sqrt(var));
    }
}

// ---------------------------------------------------------------- QKV GEMM
// V-blocks (bx>=16) hold one full head's 64n x 64d tile: stage in LDS and
// write vt coalesced (n-contiguous) instead of the d-scatter.
__global__ __launch_bounds__(256) void qkv_gemm(
    const unsigned short* __restrict__ x, const unsigned short* __restrict__ w,
    const float* __restrict__ b,
    unsigned short* __restrict__ q, unsigned short* __restrict__ k,
    unsigned short* __restrict__ vt) {
    __shared__ unsigned short vstage[64][72];   // 9216 B; padded rows (16B-aligned)
    int lane = threadIdx.x & 63, wave = threadIdx.x >> 6;
    int l16 = lane & 15, quad = lane >> 4;
    int m0 = blockIdx.y * 64 + wave * 16;
    int n0 = blockIdx.x * 64;

    const unsigned short* arow = x + (size_t)(m0 + l16) * 512 + quad * 8;
    f32x4 acc[4];
#pragma unroll
    for (int nb = 0; nb < 4; nb++) acc[nb] = (f32x4){0.f, 0.f, 0.f, 0.f};

    for (int k0 = 0; k0 < 512; k0 += 32) {
        bf16x8 af = *(const bf16x8*)(arow + k0);
#pragma unroll
        for (int nb = 0; nb < 4; nb++) {
            bf16x8 bf = *(const bf16x8*)(w + (size_t)(n0 + nb * 16 + l16) * 512 + k0 + quad * 8);
            acc[nb] = MFMA16(af, bf, acc[nb]);
        }
    }
    if (blockIdx.x < 16) {                 // q / k blocks: direct store
#pragma unroll
        for (int nb = 0; nb < 4; nb++) {
            int j = n0 + nb * 16 + l16;
            float bj = b[j];
            int s = j >> 9;                // 0=q 1=k
            int rem = j & 511;
            int h = rem >> 6, d = rem & 63;
#pragma unroll
            for (int r = 0; r < 4; r++) {
                int n = m0 + quad * 4 + r;
                unsigned short u = f2b(acc[nb][r] + bj);
                if (s == 0) q[((size_t)h * 4096 + n) * 64 + d] = u;
                else        k[((size_t)h * 4096 + n) * 64 + d] = u;
            }
        }
    } else {                               // V block: one head, transpose via LDS
        int h = blockIdx.x - 16;
#pragma unroll
        for (int nb = 0; nb < 4; nb++) {
            int d = nb * 16 + l16;
            float bj = b[1024 + h * 64 + d];
#pragma unroll
            for (int r = 0; r < 4; r++)
                vstage[d][wave * 16 + quad * 4 + r] = f2b(acc[nb][r] + bj);
        }
        __syncthreads();
        int t = threadIdx.x;
        int d = t >> 2;                    // 0..63
        int nq = (t & 3) * 16;             // 0,16,32,48
        unsigned short* dst = vt + ((size_t)h * 64 + d) * 4096 + blockIdx.y * 64 + nq;
        const unsigned short* src = &vstage[d][nq];
        *(uint4*)dst = *(const uint4*)src;
        *(uint4*)(dst + 8) = *(const uint4*)(src + 8);
    }
}

// ---------------------------------------------------------------- flash attention
// Block = (head, 16 q-rows), q-group-major: h = blockIdx&7, q0 = blockIdx>>3.
// 4 waves x 1024-wide KV quarters; online softmax with lambda-deferral;
// float4 bias loads (permuted dist); launch_bounds (256,4) = 128-reg budget.
__global__ __launch_bounds__(256, 4) void attn_kernel(
    const unsigned short* __restrict__ q, const unsigned short* __restrict__ k,
    const unsigned short* __restrict__ vt, const float* __restrict__ dist,
    const float* __restrict__ nis_p, unsigned short* __restrict__ att) {
    __shared__ __align__(16) char smem[16896];   // pbuf 4x(16x72)u16 | obuf+mlbuf
    int lane = threadIdx.x & 63, wave = threadIdx.x >> 6;
    int l16 = lane & 15, quad = lane >> 4;
    int h = blockIdx.x & 7;              // q-group-major swizzle
    int q0 = (blockIdx.x >> 3) * 16;
    int kvbase = wave * 1024;
    float nis = *nis_p;
    const float scale = 0.125f;

    short* pb = (short*)smem + wave * 1152;   // 16 x 72

    const unsigned short* qbase = q + ((size_t)h * 4096 + q0 + l16) * 64 + quad * 8;
    bf16x8 qf0 = *(const bf16x8*)(qbase);
    bf16x8 qf1 = *(const bf16x8*)(qbase + 32);

    f32x4 o[4];
    float m[4], lam[4];
#pragma unroll
    for (int r = 0; r < 4; r++) {
        m[r] = -1e30f; lam[r] = 0.f;
        o[0][r] = 0.f; o[1][r] = 0.f; o[2][r] = 0.f; o[3][r] = 0.f;
    }

    for (int kv0 = kvbase; kv0 < kvbase + 1024; kv0 += 64) {
        f32x4 s[4];
#pragma unroll
        for (int cb = 0; cb < 4; cb++) {
            const unsigned short* kbase =
                k + ((size_t)h * 4096 + kv0 + cb * 16 + l16) * 64 + quad * 8;
            bf16x8 kf0 = *(const bf16x8*)(kbase);
            bf16x8 kf1 = *(const bf16x8*)(kbase + 32);
            f32x4 z = (f32x4){0.f, 0.f, 0.f, 0.f};
            z = MFMA16(qf0, kf0, z);
            z = MFMA16(qf1, kf1, z);
            s[cb] = z;
        }
        // bias: one float4 per r (permuted dist: .x->cb0 .y->cb1 .z->cb2 .w->cb3)
#pragma unroll
        for (int r = 0; r < 4; r++) {
            float4 dv = *(const float4*)(dist +
                (size_t)(q0 + quad * 4 + r) * 4096 + kv0 + l16 * 4);
            s[0][r] = s[0][r] * scale + dv.x * nis;
            s[1][r] = s[1][r] * scale + dv.y * nis;
            s[2][r] = s[2][r] * scale + dv.z * nis;
            s[3][r] = s[3][r] * scale + dv.w * nis;
        }
        // row max
        float mt[4];
#pragma unroll
        for (int r = 0; r < 4; r++) {
            float v = fmaxf(fmaxf(s[0][r], s[1][r]), fmaxf(s[2][r], s[3][r]));
#pragma unroll
            for (int off = 1; off < 16; off <<= 1)
                v = fmaxf(v, __shfl_xor(v, off, 64));
            mt[r] = v;
        }
        float al[4];
#pragma unroll
        for (int r = 0; r < 4; r++) {
            float mn = fmaxf(m[r], mt[r]);
            al[r] = __expf(m[r] - mn);
            m[r] = mn;
        }
        // per-lane tile sums (lambda-deferral: no shuffles here)
        float ts[4] = {0.f, 0.f, 0.f, 0.f};
#pragma unroll
        for (int cb = 0; cb < 4; cb++)
#pragma unroll
            for (int r = 0; r < 4; r++) {
                float p = __expf(s[cb][r] - m[r]);
                ts[r] += p;
                s[cb][r] = p;
            }
#pragma unroll
        for (int r = 0; r < 4; r++) {
            lam[r] = lam[r] * al[r] + ts[r];
            o[0][r] *= al[r]; o[1][r] *= al[r]; o[2][r] *= al[r]; o[3][r] *= al[r];
        }
        // P (C-layout) -> LDS -> A-operand layout
#pragma unroll
        for (int cb = 0; cb < 4; cb++)
#pragma unroll
            for (int r = 0; r < 4; r++)
                pb[(quad * 4 + r) * 72 + cb * 16 + l16] = (short)f2b(s[cb][r]);
        bf16x8 pf0 = *(const bf16x8*)(pb + l16 * 72 + quad * 8);
        bf16x8 pf1 = *(const bf16x8*)(pb + l16 * 72 + 32 + quad * 8);
#pragma unroll
        for (int db = 0; db < 4; db++) {
            const unsigned short* vbase =
                vt + ((size_t)h * 64 + db * 16 + l16) * 4096 + kv0 + quad * 8;
            bf16x8 vf0 = *(const bf16x8*)(vbase);
            bf16x8 vf1 = *(const bf16x8*)(vbase + 32);
            o[db] = MFMA16(pf0, vf0, o[db]);
            o[db] = MFMA16(pf1, vf1, o[db]);
        }
    }

    // deferred row-sum reduction
#pragma unroll
    for (int r = 0; r < 4; r++)
#pragma unroll
        for (int off = 1; off < 16; off <<= 1)
            lam[r] += __shfl_xor(lam[r], off, 64);

    // -------- block-level merge of 4 KV-chunk partials
    __syncthreads();                       // all waves done with pbuf
    float* obuf = (float*)smem;            // [4 chunk][16 row][64 d]
    float* mlbuf = (float*)(smem + 16384); // [4 chunk][16 row][2]
#pragma unroll
    for (int db = 0; db < 4; db++)
#pragma unroll
        for (int r = 0; r < 4; r++)
            obuf[(wave * 16 + quad * 4 + r) * 64 + db * 16 + l16] = o[db][r];
    if (l16 == 0)
#pragma unroll
        for (int r = 0; r < 4; r++) {
            mlbuf[(wave * 16 + quad * 4 + r) * 2 + 0] = m[r];
            mlbuf[(wave * 16 + quad * 4 + r) * 2 + 1] = lam[r];
        }
    __syncthreads();

    int d = threadIdx.x & 63;
#pragma unroll
    for (int i = 0; i < 4; i++) {
        int row = (threadIdx.x >> 6) * 4 + i;
        float m0c = mlbuf[(0 * 16 + row) * 2], m1c = mlbuf[(1 * 16 + row) * 2];
        float m2c = mlbuf[(2 * 16 + row) * 2], m3c = mlbuf[(3 * 16 + row) * 2];
        float M = fmaxf(fmaxf(m0c, m1c), fmaxf(m2c, m3c));
        float e0 = __expf(m0c - M), e1 = __expf(m1c - M);
        float e2 = __expf(m2c - M), e3 = __expf(m3c - M);
        float L = mlbuf[(0 * 16 + row) * 2 + 1] * e0 + mlbuf[(1 * 16 + row) * 2 + 1] * e1
                + mlbuf[(2 * 16 + row) * 2 + 1] * e2 + mlbuf[(3 * 16 + row) * 2 + 1] * e3;
        float O = obuf[(0 * 16 + row) * 64 + d] * e0 + obuf[(1 * 16 + row) * 64 + d] * e1
                + obuf[(2 * 16 + row) * 64 + d] * e2 + obuf[(3 * 16 + row) * 64 + d] * e3;
        att[(size_t)(q0 + row) * 512 + h * 64 + d] = f2b(O / L);
    }
}

// ---------------------------------------------------------------- output GEMM (fp32 store)
__global__ __launch_bounds__(256) void out_gemm(
    const unsigned short* __restrict__ att, const unsigned short* __restrict__ w,
    const float* __restrict__ b, float* __restrict__ out) {
    int lane = threadIdx.x & 63, wave = threadIdx.x >> 6;
    int l16 = lane & 15, quad = lane >> 4;
    int m0 = blockIdx.y * 64 + wave * 16;
    int n0 = blockIdx.x * 64;

    const unsigned short* arow = att + (size_t)(m0 + l16) * 512 + quad * 8;
    f32x4 acc[4];
#pragma unroll
    for (int nb = 0; nb < 4; nb++) acc[nb] = (f32x4){0.f, 0.f, 0.f, 0.f};

    for (int k0 = 0; k0 < 512; k0 += 32) {
        bf16x8 af = *(const bf16x8*)(arow + k0);
#pragma unroll
        for (int nb = 0; nb < 4; nb++) {
            bf16x8 bf = *(const bf16x8*)(w + (size_t)(n0 + nb * 16 + l16) * 512 + k0 + quad * 8);
            acc[nb] = MFMA16(af, bf, acc[nb]);
        }
    }
#pragma unroll
    for (int nb = 0; nb < 4; nb++) {
        float bj = b[n0 + nb * 16 + l16];
#pragma unroll
        for (int r = 0; r < 4; r++)
            out[(size_t)(m0 + quad * 4 + r) * 512 + n0 + nb * 16 + l16] =
                acc[nb][r] + bj;
    }
}

extern "C" void kernel_launch(void* const* d_in, const int* in_sizes, int n_in,
                              void* d_out, int out_size, void* d_ws, size_t ws_size,
                              hipStream_t stream) {
    const float* x    = (const float*)d_in[0];
    const float* lat  = (const float*)d_in[1];
    const float* lon  = (const float*)d_in[2];
    const float* wqkv = (const float*)d_in[3];
    const float* bqkv = (const float*)d_in[4];
    const float* wout = (const float*)d_in[5];
    const float* bout = (const float*)d_in[6];
    float* out = (float*)d_out;

    char* ws = (char*)d_ws;
    float* dist        = (float*)ws;                                  // 64 MiB
    double* partials   = (double*)(ws + 67108864);                    // 64 KiB
    float* nis         = (float*)(ws + 67108864 + 65536);             // 64 B
    unsigned short* q  = (unsigned short*)(ws + 67108864 + 65600);
    unsigned short* k  = q  + (size_t)8 * 4096 * 64;   // 4 MiB each
    unsigned short* vt = k  + (size_t)8 * 4096 * 64;
    unsigned short* att = vt + (size_t)8 * 4096 * 64;
    unsigned short* xb  = att + (size_t)4096 * 512;
    unsigned short* wqb = xb  + (size_t)4096 * 512;
    unsigned short* wob = wqb + (size_t)1536 * 512;

    cvt_kernel<<<2048, 256, 0, stream>>>(x, xb, 4096 * 512);
    cvt_kernel<<<768, 256, 0, stream>>>(wqkv, wqb, 1536 * 512);
    cvt_kernel<<<256, 256, 0, stream>>>(wout, wob, 512 * 512);
    dist_kernel<<<4096, 256, 0, stream>>>(lat, lon, dist, partials);
    stats_kernel<<<1, 256, 0, stream>>>(partials, nis);
    qkv_gemm<<<dim3(24, 64), 256, 0, stream>>>(xb, wqb, bqkv, q, k, vt);
    attn_kernel<<<2048, 256, 0, stream>>>(q, k, vt, dist, nis, att);
    out_gemm<<<dim3(8, 64), 256, 0, stream>>>(att, wob, bout, out);
}